// Round 3
// baseline (2503.919 us; speedup 1.0000x reference)
//
#include <hip/hip_runtime.h>

#define B 8
#define N 8192
#define S 2048
#define K 32
#define TPB 512           // all blocks: 8 waves
#define PPT (N / TPB)     // 16 contiguous points per FPS thread
#define HPT (PPT / 2)     // 8 float2 pairs per FPS thread
#define CHUNK_STEP 128    // FPS publish cadence
#define WPB 31            // worker blocks per batch
#define WVB (WPB * 8)     // 248 KNN waves per batch (stride)

typedef float v2f __attribute__((ext_vector_type(2)));

// Exact (no-FMA, left-to-right) squared distance to match numpy fp32:
// ((dx*dx + dy*dy) + dz*dz). FPS argmax is a chaotic recurrence; any ulp
// difference diverges the center sequence. Verified absmax==0 (R1-R10).
__device__ __forceinline__ float sqdist3(float ax, float ay, float az,
                                         float bx, float by, float bz) {
    float dx = ax - bx, dy = ay - by, dz = az - bz;
    return __fadd_rn(__fadd_rn(__fmul_rn(dx, dx), __fmul_rn(dy, dy)),
                     __fmul_rn(dz, dz));
}

template <int CTRL>
__device__ __forceinline__ float dpp_fmax(float v) {
    const int iv = __float_as_int(v);
    const int sh = __builtin_amdgcn_update_dpp(iv, iv, CTRL, 0xF, 0xF, false);
    return fmaxf(v, __int_as_float(sh));
}
__device__ __forceinline__ float wave_fmax_dpp(float v) {
    v = dpp_fmax<0x111>(v);  // row_shr:1
    v = dpp_fmax<0x112>(v);  // row_shr:2
    v = dpp_fmax<0x114>(v);  // row_shr:4
    v = dpp_fmax<0x118>(v);  // row_shr:8
    v = dpp_fmax<0x142>(v);  // row_bcast:15
    v = dpp_fmax<0x143>(v);  // row_bcast:31 -> lane 63 = wave max
    return __int_as_float(__builtin_amdgcn_readlane(__float_as_int(v), 63));
}

// ---------------------------------------------------------------------------
// R11: packed-fp32 md update (issue-width cut on the dominant phase).
//  - R10 post-mortem: direct stores + inline coord publish = -360 us; step
//    cost now ~1.06 us = ~2540 cyc. Largest issue slice per SIMD is the
//    16-point distance/min update (~640 cyc, 2 waves x ~160 scalar VALU x
//    2 cyc). gfx950 has packed fp32 (v_pk_add/mul_f32, VOP3P): two IEEE-rn
//    fp32 lanes per instruction, bit-identical per component.
//  - State is now float2 pairs (x2/y2/z2/md2[8]); update per pair = 3 pk_sub
//    + 3 pk_mul + 2 pk_add + 2 scalar v_min = ~96 instr/wave vs ~160.
//  - Exactness: `#pragma clang fp contract(off)` at kernel scope blocks FMA
//    contraction; packed add/mul round per-component exactly like the scalar
//    __fadd_rn/__fmul_rn chain; association ((dx*dx+dy*dy)+dz*dz) unchanged.
//    Owner tie-break chain re-expressed over pair components in the SAME
//    descending-i order (j desc, .y then .x) -> lowest matching i still wins.
//  - Worker path untouched.
// Tie-break invariants unchanged: FPS (max dist, min gid): thread = lowest i
// (descending overwrite), wave = lowest lane (ballot ctz), block = lowest wid
// (strict > scan from w=0); KNN (d, idx) lexicographic == stable top_k.
// absmax must stay 0.
// ---------------------------------------------------------------------------
__global__ __launch_bounds__(TPB, 2) void fused_kernel(
    const float* __restrict__ xyz, float* __restrict__ out,
    float* __restrict__ centers, unsigned* __restrict__ progress) {
#pragma clang fp contract(off)
    const int blk = blockIdx.x;
    const int t = threadIdx.x;
    const int lane = t & 63;

    __shared__ float4 pub[2][8];       // per-wave {wmax,x,y,z}, dbuf

    if (blk < B) {
        // =================== FPS producer ===================
        const int b = blk;
        const float* xb = xyz + (size_t)b * N * 3;
        float* cb = centers + (size_t)b * S * 3;
        const int wid = t >> 6;

        v2f x2[HPT], y2[HPT], z2[HPT], md2[HPT];
        {
            float raw[3 * PPT];
            const float4* src = (const float4*)(xb + 3 * PPT * t);
#pragma unroll
            for (int i = 0; i < 3 * PPT / 4; ++i) {
                const float4 v = src[i];
                raw[4 * i + 0] = v.x; raw[4 * i + 1] = v.y;
                raw[4 * i + 2] = v.z; raw[4 * i + 3] = v.w;
            }
#pragma unroll
            for (int j = 0; j < HPT; ++j) {
                x2[j] = (v2f){raw[6 * j + 0], raw[6 * j + 3]};
                y2[j] = (v2f){raw[6 * j + 1], raw[6 * j + 4]};
                z2[j] = (v2f){raw[6 * j + 2], raw[6 * j + 5]};
                md2[j] = (v2f){INFINITY, INFINITY};
            }
        }

        float px = xb[0], py = xb[1], pz = xb[2];   // step 0: point 0
        if (t == 0) { cb[0] = px; cb[1] = py; cb[2] = pz; }

        for (int s = 1; s < S; ++s) {
            // packed local update; scalar tree max (values only, all static)
            float m[PPT];
            {
                const v2f pxx = {px, px}, pyy = {py, py}, pzz = {pz, pz};
#pragma unroll
                for (int j = 0; j < HPT; ++j) {
                    const v2f dx = x2[j] - pxx;
                    const v2f dy = y2[j] - pyy;
                    const v2f dz = z2[j] - pzz;
                    const v2f d2 = ((dx * dx) + (dy * dy)) + (dz * dz);
                    const float a = fminf(md2[j].x, d2.x);
                    const float c = fminf(md2[j].y, d2.y);
                    md2[j] = (v2f){a, c};
                    m[2 * j + 0] = a;
                    m[2 * j + 1] = c;
                }
            }
#pragma unroll
            for (int st = 1; st < PPT; st <<= 1)
#pragma unroll
                for (int i = 0; i < PPT; i += 2 * st)
                    m[i] = fmaxf(m[i], m[i + st]);
            const float best = m[0];

            // wave max (DPP) + first-lane tie-break via ballot
            const float wmax = wave_fmax_dpp(best);
            const unsigned long long mb = __ballot(best == wmax);
            const int ol = (int)__builtin_ctzll(mb);

            // owner: statically-indexed descending overwrite selects the
            // lowest-i match's coords (pure cndmask chain, no dynamic
            // register indexing). Pair order: j desc, .y (i=2j+1) before
            // .x (i=2j) -> identical to scalar i = PPT-1..0.
            const int pb = s & 1;
            if (lane == ol) {
                float bx = x2[0].x, by = y2[0].x, bz = z2[0].x;
#pragma unroll
                for (int j = HPT - 1; j >= 0; --j) {
                    if (md2[j].y == wmax) { bx = x2[j].y; by = y2[j].y; bz = z2[j].y; }
                    if (md2[j].x == wmax) { bx = x2[j].x; by = y2[j].x; bz = z2[j].x; }
                }
                pub[pb][wid] = make_float4(wmax, bx, by, bz);
            }
            __syncthreads();               // the ONLY per-step barrier

            // serial scan of 8 wave winners (strict > -> lowest wid on ties)
            float4 v0 = pub[pb][0];
            float gmax = v0.x;
            px = v0.y; py = v0.z; pz = v0.w;
#pragma unroll
            for (int w = 1; w < 8; ++w) {
                const float4 u = pub[pb][w];
                const bool g = u.x > gmax;
                gmax = g ? u.x : gmax;
                px = g ? u.y : px;
                py = g ? u.z : py;
                pz = g ? u.w : pz;
            }

            // t0 streams the center straight to global (only t0 ever writes
            // centers; fire-and-forget, drained by the release below)
            if (t == 0) {
                float* cs = cb + 3 * s;
                cs[0] = px; cs[1] = py; cs[2] = pz;
            }

            // chunk publish: release store orders t0's prior center stores
            // (compiler emits vmcnt(0) drain + agent-scope writeback)
            if ((s & (CHUNK_STEP - 1)) == (CHUNK_STEP - 1)) {
                if (t == 0)
                    __hip_atomic_store(&progress[b], (unsigned)(s + 1),
                                       __ATOMIC_RELEASE, __HIP_MEMORY_SCOPE_AGENT);
            }
        }
    } else {
        // ======================= KNN workers ===============================
        const int w = blk - B;
        const int b = w & 7;               // same XCD as FPS block b (%8 rr)
        const int wchunk = w >> 3;         // 0..30
        const int waveid = wchunk * 8 + (t >> 6);   // 0..247 within batch
        const float* xb = xyz + (size_t)b * N * 3;

        unsigned seen = 0;                 // register-cached progress[b]
        for (int s = waveid; s < S; s += WVB) {
            // wait until progress[b] > s (all lanes load same line ->
            // broadcast; ACQUIRE invalidates L1 so center reads are fresh)
            while (seen <= (unsigned)s) {
                seen = __hip_atomic_load(&progress[b], __ATOMIC_ACQUIRE,
                                         __HIP_MEMORY_SCOPE_AGENT);
                if (seen <= (unsigned)s) __builtin_amdgcn_s_sleep(64);
            }

            const float* c = centers + (size_t)(b * S + s) * 3;
            const float cx = c[0], cy = c[1], cz = c[2];

            unsigned long long P = ~0ULL;   // lanes 0..31: sorted top-32 (asc)
            unsigned long long tau = ~0ULL;

            for (int i = 0; i < N / 64; ++i) {
                const int p = (i << 6) + lane;
                const float* q = xb + 3 * p;
                const float d = sqdist3(q[0], q[1], q[2], cx, cy, cz);
                const unsigned long long cand =
                    ((unsigned long long)__float_as_uint(d) << 32) | (unsigned)p;
                bool alive = cand < tau;
                unsigned long long mask = __ballot(alive);
                while (mask) {
                    const int src = __builtin_ctzll(mask);
                    const unsigned long long bc = __shfl(cand, src);
                    unsigned long long up = __shfl_up(P, 1);
                    if (lane == 0) up = bc;
                    const bool gt = P > bc;
                    const unsigned long long shifted = (up > bc) ? up : bc;
                    P = gt ? shifted : P;
                    tau = __shfl(P, 31);
                    if (lane == src) alive = false;
                    alive = alive && (cand < tau);
                    mask = __ballot(alive);
                }
            }

            if (lane < K) {
                const unsigned nidx = (unsigned)P;
                const float* q = xb + 3 * nidx;
                float* o = out + ((size_t)(b * S + s) * K + lane) * 3;
                o[0] = q[0] - cx;
                o[1] = q[1] - cy;
                o[2] = q[2] - cz;
            }
        }
    }
}

extern "C" void kernel_launch(void* const* d_in, const int* in_sizes, int n_in,
                              void* d_out, int out_size, void* d_ws, size_t ws_size,
                              hipStream_t stream) {
    const float* xyz = (const float*)d_in[0];
    float* out = (float*)d_out;                         // neighborhood [B,S,K,3]
    float* centers = out + (size_t)B * S * K * 3;       // centers [B,S,3]
    unsigned* progress = (unsigned*)d_ws;               // [B] centers-ready count

    // d_ws is poisoned 0xAA before every timed launch -> must zero progress
    hipMemsetAsync(d_ws, 0, B * sizeof(unsigned), stream);

    fused_kernel<<<B + WPB * B, TPB, 0, stream>>>(xyz, out, centers, progress);
}

// Round 4
// 2186.503 us; speedup vs baseline: 1.1452x; 1.1452x over previous
//
#include <hip/hip_runtime.h>

#define B 8
#define N 8192
#define S 2048
#define K 32
#define TPB 512           // all blocks: 8 waves
#define PPT (N / TPB)     // 16 contiguous points per FPS thread
#define CHUNK_STEP 128    // FPS publish cadence
#define WPB 30            // worker blocks per batch (grid 248 <= 256 CUs)
#define WVB (WPB * 8)     // 240 KNN waves per batch (stride)

// Exact (no-FMA, left-to-right) squared distance to match numpy fp32:
// ((dx*dx + dy*dy) + dz*dz). FPS argmax is a chaotic recurrence; any ulp
// difference diverges the center sequence. Verified absmax==0 (R1-R11).
__device__ __forceinline__ float sqdist3(float ax, float ay, float az,
                                         float bx, float by, float bz) {
    float dx = ax - bx, dy = ay - by, dz = az - bz;
    return __fadd_rn(__fadd_rn(__fmul_rn(dx, dx), __fmul_rn(dy, dy)),
                     __fmul_rn(dz, dz));
}

template <int CTRL>
__device__ __forceinline__ float dpp_fmax(float v) {
    const int iv = __float_as_int(v);
    const int sh = __builtin_amdgcn_update_dpp(iv, iv, CTRL, 0xF, 0xF, false);
    return fmaxf(v, __int_as_float(sh));
}
__device__ __forceinline__ float wave_fmax_dpp(float v) {
    v = dpp_fmax<0x111>(v);  // row_shr:1
    v = dpp_fmax<0x112>(v);  // row_shr:2
    v = dpp_fmax<0x114>(v);  // row_shr:4
    v = dpp_fmax<0x118>(v);  // row_shr:8
    v = dpp_fmax<0x142>(v);  // row_bcast:15
    v = dpp_fmax<0x143>(v);  // row_bcast:31 -> lane 63 = wave max
    return __int_as_float(__builtin_amdgcn_readlane(__float_as_int(v), 63));
}

// ---------------------------------------------------------------------------
// R12: R10 hot code verbatim (best: 2164 us, VGPR 44) + CU-exclusivity.
//  - R11 post-mortem: compiler-lowered v2f "packed fp32" added cross-half
//    moves (+340 us, VGPR 68). Reverted to R10's scalar update.
//  - NEW: pub[] is oversized to 83.2 KB of LDS. 160 KB/CU / 83.2 KB -> max
//    ONE block per CU. Previously (512 B LDS, 44 VGPR) up to 4 blocks/CU
//    could co-reside, so KNN worker blocks sharing an FPS CU stole up to
//    6/8 of the SIMD issue slots during each post-publish KNN burst (~70%
//    duty) -- a candidate for the ~900 unexplained cycles/step. Now every
//    block owns its CU: FPS issue is exclusive.
//  - WPB 31 -> 30: grid = 8 + 240 = 248 blocks <= 256 CUs, all resident at
//    1 block/CU. Deadlock-free regardless of placement (workers wait only on
//    FPS progress; FPS waits on nobody). 240 waves/batch >= 128-center chunk
//    -> each wave handles <=1 center per chunk; tail after final publish is
//    ~1 KNN scan.
// Tie-break invariants unchanged: FPS (max dist, min gid): thread = lowest i
// (descending overwrite), wave = lowest lane (ballot ctz), block = lowest wid
// (strict > scan from w=0); KNN (d, idx) lexicographic == stable top_k.
// absmax must stay 0.
// ---------------------------------------------------------------------------
__global__ __launch_bounds__(TPB, 2) void fused_kernel(
    const float* __restrict__ xyz, float* __restrict__ out,
    float* __restrict__ centers, unsigned* __restrict__ progress) {
    const int blk = blockIdx.x;
    const int t = threadIdx.x;
    const int lane = t & 63;

    // 2 x 2600 x 16 B = 83.2 KB -> forces 1 block/CU (only [pb][0..7] used;
    // the oversizing exists purely to make every block CU-exclusive).
    __shared__ float4 pub[2][2600];

    if (blk < B) {
        // =================== FPS producer ===================
        const int b = blk;
        const float* xb = xyz + (size_t)b * N * 3;
        float* cb = centers + (size_t)b * S * 3;
        const int wid = t >> 6;

        float x[PPT], y[PPT], z[PPT], md[PPT];
        {
            float raw[3 * PPT];
            const float4* src = (const float4*)(xb + 3 * PPT * t);
#pragma unroll
            for (int i = 0; i < 3 * PPT / 4; ++i) {
                const float4 v = src[i];
                raw[4 * i + 0] = v.x; raw[4 * i + 1] = v.y;
                raw[4 * i + 2] = v.z; raw[4 * i + 3] = v.w;
            }
#pragma unroll
            for (int i = 0; i < PPT; ++i) {
                x[i] = raw[3 * i + 0];
                y[i] = raw[3 * i + 1];
                z[i] = raw[3 * i + 2];
                md[i] = INFINITY;
            }
        }

        float px = xb[0], py = xb[1], pz = xb[2];   // step 0: point 0
        if (t == 0) { cb[0] = px; cb[1] = py; cb[2] = pz; }

        for (int s = 1; s < S; ++s) {
            // local update; tree max (values only, all static indices)
            float m[PPT];
#pragma unroll
            for (int i = 0; i < PPT; ++i) {
                const float d = sqdist3(x[i], y[i], z[i], px, py, pz);
                m[i] = fminf(md[i], d);
                md[i] = m[i];
            }
#pragma unroll
            for (int st = 1; st < PPT; st <<= 1)
#pragma unroll
                for (int i = 0; i < PPT; i += 2 * st)
                    m[i] = fmaxf(m[i], m[i + st]);
            const float best = m[0];

            // wave max (DPP) + first-lane tie-break via ballot
            const float wmax = wave_fmax_dpp(best);
            const unsigned long long mb = __ballot(best == wmax);
            const int ol = (int)__builtin_ctzll(mb);

            // owner: statically-indexed descending overwrite selects the
            // lowest-i match's coords (pure cndmask chain, no dynamic
            // register indexing anywhere) and publishes them inline.
            const int pb = s & 1;
            if (lane == ol) {
                float bx = x[0], by = y[0], bz = z[0];
#pragma unroll
                for (int i = PPT - 1; i >= 0; --i)
                    if (md[i] == wmax) { bx = x[i]; by = y[i]; bz = z[i]; }
                pub[pb][wid] = make_float4(wmax, bx, by, bz);
            }
            __syncthreads();               // the ONLY per-step barrier

            // serial scan of 8 wave winners (strict > -> lowest wid on ties)
            float4 v0 = pub[pb][0];
            float gmax = v0.x;
            px = v0.y; py = v0.z; pz = v0.w;
#pragma unroll
            for (int w = 1; w < 8; ++w) {
                const float4 u = pub[pb][w];
                const bool g = u.x > gmax;
                gmax = g ? u.x : gmax;
                px = g ? u.y : px;
                py = g ? u.z : py;
                pz = g ? u.w : pz;
            }

            // t0 streams the center straight to global (only t0 ever writes
            // centers; fire-and-forget, drained by the release below)
            if (t == 0) {
                float* cs = cb + 3 * s;
                cs[0] = px; cs[1] = py; cs[2] = pz;
            }

            // chunk publish: release store orders t0's prior center stores
            // (compiler emits vmcnt(0) drain + agent-scope writeback)
            if ((s & (CHUNK_STEP - 1)) == (CHUNK_STEP - 1)) {
                if (t == 0)
                    __hip_atomic_store(&progress[b], (unsigned)(s + 1),
                                       __ATOMIC_RELEASE, __HIP_MEMORY_SCOPE_AGENT);
            }
        }
    } else {
        // ======================= KNN workers ===============================
        const int w = blk - B;
        const int b = w & 7;               // same XCD as FPS block b (%8 rr)
        const int wchunk = w >> 3;         // 0..29
        const int waveid = wchunk * 8 + (t >> 6);   // 0..239 within batch
        const float* xb = xyz + (size_t)b * N * 3;

        unsigned seen = 0;                 // register-cached progress[b]
        for (int s = waveid; s < S; s += WVB) {
            // wait until progress[b] > s (all lanes load same line ->
            // broadcast; ACQUIRE invalidates L1 so center reads are fresh)
            while (seen <= (unsigned)s) {
                seen = __hip_atomic_load(&progress[b], __ATOMIC_ACQUIRE,
                                         __HIP_MEMORY_SCOPE_AGENT);
                if (seen <= (unsigned)s) __builtin_amdgcn_s_sleep(64);
            }

            const float* c = centers + (size_t)(b * S + s) * 3;
            const float cx = c[0], cy = c[1], cz = c[2];

            unsigned long long P = ~0ULL;   // lanes 0..31: sorted top-32 (asc)
            unsigned long long tau = ~0ULL;

            for (int i = 0; i < N / 64; ++i) {
                const int p = (i << 6) + lane;
                const float* q = xb + 3 * p;
                const float d = sqdist3(q[0], q[1], q[2], cx, cy, cz);
                const unsigned long long cand =
                    ((unsigned long long)__float_as_uint(d) << 32) | (unsigned)p;
                bool alive = cand < tau;
                unsigned long long mask = __ballot(alive);
                while (mask) {
                    const int src = __builtin_ctzll(mask);
                    const unsigned long long bc = __shfl(cand, src);
                    unsigned long long up = __shfl_up(P, 1);
                    if (lane == 0) up = bc;
                    const bool gt = P > bc;
                    const unsigned long long shifted = (up > bc) ? up : bc;
                    P = gt ? shifted : P;
                    tau = __shfl(P, 31);
                    if (lane == src) alive = false;
                    alive = alive && (cand < tau);
                    mask = __ballot(alive);
                }
            }

            if (lane < K) {
                const unsigned nidx = (unsigned)P;
                const float* q = xb + 3 * nidx;
                float* o = out + ((size_t)(b * S + s) * K + lane) * 3;
                o[0] = q[0] - cx;
                o[1] = q[1] - cy;
                o[2] = q[2] - cz;
            }
        }
    }
}

extern "C" void kernel_launch(void* const* d_in, const int* in_sizes, int n_in,
                              void* d_out, int out_size, void* d_ws, size_t ws_size,
                              hipStream_t stream) {
    const float* xyz = (const float*)d_in[0];
    float* out = (float*)d_out;                         // neighborhood [B,S,K,3]
    float* centers = out + (size_t)B * S * K * 3;       // centers [B,S,3]
    unsigned* progress = (unsigned*)d_ws;               // [B] centers-ready count

    // d_ws is poisoned 0xAA before every timed launch -> must zero progress
    hipMemsetAsync(d_ws, 0, B * sizeof(unsigned), stream);

    fused_kernel<<<B + WPB * B, TPB, 0, stream>>>(xyz, out, centers, progress);
}